// Round 7
// baseline (46.627 us; speedup 1.0000x reference)
//
#include <hip/hip_runtime.h>

#define BATCH 8192
#define DIM 128
#define NCLS 6
#define NPAIRS 15
#define NBLK 256
#define NTHR 1024
#define WPB (NTHR / 64)           // 16 waves per block
#define NWAVES (NBLK * WPB)       // 4096 waves
#define RPW (BATCH / NWAVES)      // 2 rows per wave -> 1 pair-iter
#define ZLEN (NCLS * DIM)         // 768
#define MAGIC 0x5CA1AB1Eu

// d_ws layout: float gpart[NBLK][ZLEN]; float gcntp[NBLK][NCLS]; uint flags[NBLK]
// ≈ 794 KB. All cross-block traffic via RELAXED/AGENT atomics (sc1 ->
// Infinity-Cache coherence point; no L2 flushes). gpart/gcntp fully
// rewritten every call; flags self-restoring (block 0 consumes MAGIC back
// to 0); any initial flag value != MAGIC (0xAA poison, zeros) is safe.

__global__ __launch_bounds__(NTHR) void fused_kernel(
    const float* __restrict__ latent,
    const int* __restrict__ label,
    float* __restrict__ gpart,
    float* __restrict__ gcntp,
    unsigned int* __restrict__ flags,
    float* __restrict__ out)
{
    __shared__ float lz[WPB][ZLEN];
    __shared__ int   lcnt[WPB][NCLS];

    const int tid  = threadIdx.x;
    const int lane = tid & 63;
    const int w    = tid >> 6;
    const int half = lane >> 5;        // which row of the wave's pair
    const int hl   = lane & 31;        // lane within 32-lane half
    const int gw   = blockIdx.x * WPB + w;
    const int row  = gw * RPW + half;  // this half handles exactly one row

    // ---- Phase A: one float4 load per thread, one row per 32-lane half ----
    const float4 v = *reinterpret_cast<const float4*>(
        latent + (size_t)row * DIM + hl * 4);
    const int lab = label[row];

    float ss = v.x * v.x + v.y * v.y + v.z * v.z + v.w * v.w;
    #pragma unroll
    for (int off = 16; off >= 1; off >>= 1)
        ss += __shfl_xor(ss, off);                 // reduce within 32-lane half
    const float rn = 1.0f / sqrtf(ss);             // correctly-rounded (no rsqrt bias)

    float4 acc[NCLS];
    int    cnt[NCLS];
    #pragma unroll
    for (int c = 0; c < NCLS; ++c) {
        const float m = (lab == c) ? rn : 0.0f;    // predicated, static index
        acc[c].x = v.x * m;  acc[c].y = v.y * m;
        acc[c].z = v.z * m;  acc[c].w = v.w * m;
        cnt[c]   = (hl == 0) ? (int)(lab == c) : 0;
    }

    // fold the two 32-lane halves together
    #pragma unroll
    for (int c = 0; c < NCLS; ++c) {
        acc[c].x += __shfl_xor(acc[c].x, 32);
        acc[c].y += __shfl_xor(acc[c].y, 32);
        acc[c].z += __shfl_xor(acc[c].z, 32);
        acc[c].w += __shfl_xor(acc[c].w, 32);
        cnt[c]   += __shfl_xor(cnt[c], 32);
    }

    if (lane < 32) {
        #pragma unroll
        for (int c = 0; c < NCLS; ++c)
            *reinterpret_cast<float4*>(&lz[w][c * DIM + lane * 4]) = acc[c];
    }
    if (lane == 0) {
        #pragma unroll
        for (int c = 0; c < NCLS; ++c) lcnt[w][c] = cnt[c];
    }
    __syncthreads();

    // block-level reduce across the 16 waves -> per-block partials (sc1 stores)
    if (tid < ZLEN) {
        float s = 0.f;
        #pragma unroll
        for (int ww = 0; ww < WPB; ++ww) s += lz[ww][tid];
        __hip_atomic_store(&gpart[blockIdx.x * ZLEN + tid], s,
                           __ATOMIC_RELAXED, __HIP_MEMORY_SCOPE_AGENT);
    } else if (tid < ZLEN + NCLS) {
        const int c = tid - ZLEN;
        int s = 0;
        #pragma unroll
        for (int ww = 0; ww < WPB; ++ww) s += lcnt[ww][c];
        __hip_atomic_store(&gcntp[blockIdx.x * NCLS + c], (float)s,
                           __ATOMIC_RELAXED, __HIP_MEMORY_SCOPE_AGENT);
    }

    // __syncthreads drains vmcnt(0) per wave before s_barrier, so all sc1
    // stores are acked at the coherence point before the flag is set.
    __syncthreads();
    if (tid == 0)
        __hip_atomic_store(&flags[blockIdx.x], MAGIC,
                           __ATOMIC_RELAXED, __HIP_MEMORY_SCOPE_AGENT);

    if (blockIdx.x != 0) return;

    // ---- Phase B (block 0 only): wait, reduce 256-deep, epilogue ----
    if (tid < NBLK) {
        while (__hip_atomic_load(&flags[tid], __ATOMIC_RELAXED,
                                 __HIP_MEMORY_SCOPE_AGENT) != MAGIC)
            __builtin_amdgcn_s_sleep(1);
        // consume: self-restoring flag state for next replay
        __hip_atomic_store(&flags[tid], 0u,
                           __ATOMIC_RELAXED, __HIP_MEMORY_SCOPE_AGENT);
    }
    __syncthreads();

    __shared__ float zz[ZLEN];
    __shared__ float cf[NCLS];
    __shared__ float ps[NPAIRS];

    if (tid < ZLEN) {
        float s = 0.f;
        #pragma unroll 32
        for (int b = 0; b < NBLK; ++b)
            s += __hip_atomic_load(&gpart[b * ZLEN + tid],
                                   __ATOMIC_RELAXED, __HIP_MEMORY_SCOPE_AGENT);
        zz[tid] = s;
    } else if (tid < ZLEN + NCLS) {
        const int c = tid - ZLEN;
        float s = 0.f;
        #pragma unroll 32
        for (int b = 0; b < NBLK; ++b)
            s += __hip_atomic_load(&gcntp[b * NCLS + c],
                                   __ATOMIC_RELAXED, __HIP_MEMORY_SCOPE_AGENT);
        cf[c] = s;
    }
    if (tid >= NTHR - NPAIRS) ps[tid - (NTHR - NPAIRS)] = 0.f;
    __syncthreads();

    if (tid < DIM) {
        float zi[NCLS];
        #pragma unroll
        for (int c = 0; c < NCLS; ++c) zi[c] = zz[c * DIM + tid];
        int p = 0;
        #pragma unroll
        for (int i = 0; i < NCLS; ++i) {
            #pragma unroll
            for (int j = i + 1; j < NCLS; ++j, ++p)
                atomicAdd(&ps[p], zi[i] * zi[j]);
        }
    }
    __syncthreads();

    if (tid == 0) {
        float acc2 = 0.f;
        int p = 0;
        for (int i = 0; i < NCLS; ++i) {
            const float n = cf[i];
            const float denom = fmaxf(n * n - n, 1.0f);
            for (int j = i + 1; j < NCLS; ++j, ++p)
                acc2 += ps[p] / denom;
        }
        out[0] = acc2 / (float)NPAIRS;
    }
}

extern "C" void kernel_launch(void* const* d_in, const int* in_sizes, int n_in,
                              void* d_out, int out_size, void* d_ws, size_t ws_size,
                              hipStream_t stream) {
    const float* latent = (const float*)d_in[0];
    const int* label = (const int*)d_in[1];
    float* out = (float*)d_out;

    float* gpart = (float*)d_ws;                     // [NBLK][ZLEN]
    float* gcntp = gpart + NBLK * ZLEN;              // [NBLK][NCLS]
    unsigned int* flags = (unsigned int*)(gcntp + NBLK * NCLS);  // [NBLK]

    fused_kernel<<<NBLK, NTHR, 0, stream>>>(latent, label, gpart, gcntp, flags, out);
}

// Round 8
// 40.854 us; speedup vs baseline: 1.1413x; 1.1413x over previous
//
#include <hip/hip_runtime.h>

#define BATCH 8192
#define DIM 128
#define NCLS 6
#define NPAIRS 15
#define NBLK 64
#define NTHR 1024
#define WPB (NTHR / 64)           // 16 waves per block
#define NWAVES (NBLK * WPB)       // 1024 waves
#define RPW (BATCH / NWAVES)      // 8 rows per wave
#define ITERS (RPW / 2)           // 4 pair-iters, fully unrolled
#define ZLEN (NCLS * DIM)         // 768
#define MAGIC 0x5CA1AB1Eu

// d_ws layout: float gpart[NBLK][ZLEN]; float gcntp[NBLK][NCLS]; uint flags[NBLK]
// All cross-block data via RELAXED/AGENT atomics (sc1, write-through to the
// coherence point). Flag POLLING uses atomic fetch_add(0) RMW so every poll
// executes at the coherence point (a relaxed sc1 poll load can be served
// stale from the local XCD L2 until eviction -- the R6/R7 ~38us tail).
// gpart/gcntp fully rewritten every call; flags self-restoring (block 0
// consumes MAGIC back to 0); any initial flag value != MAGIC is safe.

__global__ __launch_bounds__(NTHR) void fused_kernel(
    const float* __restrict__ latent,
    const int* __restrict__ label,
    float* __restrict__ gpart,
    float* __restrict__ gcntp,
    unsigned int* __restrict__ flags,
    float* __restrict__ out)
{
    __shared__ float lz[WPB][ZLEN];
    __shared__ int   lcnt[WPB][NCLS];

    const int tid  = threadIdx.x;
    const int lane = tid & 63;
    const int w    = tid >> 6;
    const int half = lane >> 5;        // which row of each pair
    const int hl   = lane & 31;        // lane within 32-lane half
    const int gw   = blockIdx.x * WPB + w;
    const int row0 = gw * RPW + half;  // this half handles rows row0 + 2j

    // ---- Phase A: per-block class sums ----
    const float* bp = latent + (size_t)row0 * DIM + hl * 4;
    float4 v[ITERS];
    int labs[ITERS];
    #pragma unroll
    for (int j = 0; j < ITERS; ++j)
        v[j] = *reinterpret_cast<const float4*>(bp + (size_t)j * 2 * DIM);
    #pragma unroll
    for (int j = 0; j < ITERS; ++j)
        labs[j] = label[row0 + 2 * j];

    float4 acc[NCLS];
    int    cnt[NCLS];
    #pragma unroll
    for (int c = 0; c < NCLS; ++c) { acc[c] = make_float4(0.f, 0.f, 0.f, 0.f); cnt[c] = 0; }

    #pragma unroll
    for (int j = 0; j < ITERS; ++j) {
        float ss = v[j].x * v[j].x + v[j].y * v[j].y
                 + v[j].z * v[j].z + v[j].w * v[j].w;
        #pragma unroll
        for (int off = 16; off >= 1; off >>= 1)
            ss += __shfl_xor(ss, off);                 // reduce within 32-lane half
        const float rn = 1.0f / sqrtf(ss);             // correctly-rounded (no rsqrt bias)
        const int lab = labs[j];
        #pragma unroll
        for (int c = 0; c < NCLS; ++c) {
            const float m = (lab == c) ? rn : 0.0f;    // predicated, static index
            acc[c].x += v[j].x * m;  acc[c].y += v[j].y * m;
            acc[c].z += v[j].z * m;  acc[c].w += v[j].w * m;
            cnt[c]   += (hl == 0) ? (int)(lab == c) : 0;
        }
    }

    #pragma unroll
    for (int c = 0; c < NCLS; ++c) {
        acc[c].x += __shfl_xor(acc[c].x, 32);
        acc[c].y += __shfl_xor(acc[c].y, 32);
        acc[c].z += __shfl_xor(acc[c].z, 32);
        acc[c].w += __shfl_xor(acc[c].w, 32);
        cnt[c]   += __shfl_xor(cnt[c], 32);
    }

    if (lane < 32) {
        #pragma unroll
        for (int c = 0; c < NCLS; ++c)
            *reinterpret_cast<float4*>(&lz[w][c * DIM + lane * 4]) = acc[c];
    }
    if (lane == 0) {
        #pragma unroll
        for (int c = 0; c < NCLS; ++c) lcnt[w][c] = cnt[c];
    }
    __syncthreads();

    // block-level reduce across waves -> per-block partials (sc1 atomic stores)
    if (tid < ZLEN) {
        float s = 0.f;
        #pragma unroll
        for (int ww = 0; ww < WPB; ++ww) s += lz[ww][tid];
        __hip_atomic_store(&gpart[blockIdx.x * ZLEN + tid], s,
                           __ATOMIC_RELAXED, __HIP_MEMORY_SCOPE_AGENT);
    } else if (tid < ZLEN + NCLS) {
        const int c = tid - ZLEN;
        int s = 0;
        #pragma unroll
        for (int ww = 0; ww < WPB; ++ww) s += lcnt[ww][c];
        __hip_atomic_store(&gcntp[blockIdx.x * NCLS + c], (float)s,
                           __ATOMIC_RELAXED, __HIP_MEMORY_SCOPE_AGENT);
    }

    // __syncthreads drains vmcnt(0) per wave before s_barrier, so all sc1
    // stores are acked at the coherence point before the flag is set.
    __syncthreads();
    if (tid == 0)
        __hip_atomic_store(&flags[blockIdx.x], MAGIC,
                           __ATOMIC_RELAXED, __HIP_MEMORY_SCOPE_AGENT);

    if (blockIdx.x != 0) return;

    // ---- Phase B (block 0 only): wait, reduce, epilogue ----
    if (tid < NBLK) {
        // RMW poll: executes at the coherence point every iteration
        // (cannot be served from a stale local L2 line).
        while (__hip_atomic_fetch_add(&flags[tid], 0u,
                                      __ATOMIC_RELAXED,
                                      __HIP_MEMORY_SCOPE_AGENT) != MAGIC)
            __builtin_amdgcn_s_sleep(1);
        // consume: self-restoring flag state for next replay
        __hip_atomic_store(&flags[tid], 0u,
                           __ATOMIC_RELAXED, __HIP_MEMORY_SCOPE_AGENT);
    }
    __syncthreads();

    __shared__ float zz[ZLEN];
    __shared__ float cf[NCLS];
    __shared__ float ps[NPAIRS];

    if (tid < ZLEN) {
        float s = 0.f;
        #pragma unroll 16
        for (int b = 0; b < NBLK; ++b)
            s += __hip_atomic_load(&gpart[b * ZLEN + tid],
                                   __ATOMIC_RELAXED, __HIP_MEMORY_SCOPE_AGENT);
        zz[tid] = s;
    } else if (tid < ZLEN + NCLS) {
        const int c = tid - ZLEN;
        float s = 0.f;
        #pragma unroll 16
        for (int b = 0; b < NBLK; ++b)
            s += __hip_atomic_load(&gcntp[b * NCLS + c],
                                   __ATOMIC_RELAXED, __HIP_MEMORY_SCOPE_AGENT);
        cf[c] = s;
    }
    if (tid >= NTHR - NPAIRS) ps[tid - (NTHR - NPAIRS)] = 0.f;
    __syncthreads();

    if (tid < DIM) {
        float zi[NCLS];
        #pragma unroll
        for (int c = 0; c < NCLS; ++c) zi[c] = zz[c * DIM + tid];
        int p = 0;
        #pragma unroll
        for (int i = 0; i < NCLS; ++i) {
            #pragma unroll
            for (int j = i + 1; j < NCLS; ++j, ++p)
                atomicAdd(&ps[p], zi[i] * zi[j]);
        }
    }
    __syncthreads();

    if (tid == 0) {
        float acc2 = 0.f;
        int p = 0;
        for (int i = 0; i < NCLS; ++i) {
            const float n = cf[i];
            const float denom = fmaxf(n * n - n, 1.0f);
            for (int j = i + 1; j < NCLS; ++j, ++p)
                acc2 += ps[p] / denom;
        }
        out[0] = acc2 / (float)NPAIRS;
    }
}

extern "C" void kernel_launch(void* const* d_in, const int* in_sizes, int n_in,
                              void* d_out, int out_size, void* d_ws, size_t ws_size,
                              hipStream_t stream) {
    const float* latent = (const float*)d_in[0];
    const int* label = (const int*)d_in[1];
    float* out = (float*)d_out;

    float* gpart = (float*)d_ws;                     // [NBLK][ZLEN]
    float* gcntp = gpart + NBLK * ZLEN;              // [NBLK][NCLS]
    unsigned int* flags = (unsigned int*)(gcntp + NBLK * NCLS);  // [NBLK]

    fused_kernel<<<NBLK, NTHR, 0, stream>>>(latent, label, gpart, gcntp, flags, out);
}